// Round 19
// baseline (337.555 us; speedup 1.0000x reference)
//
#include <hip/hip_runtime.h>
#include <hip/hip_bf16.h>
#include <cstdint>
#include <cstddef>

#define B_    64
#define N_    2048
#define E_    32768            // edges per graph
#define DIM_  64
#define K1_   1639
#define K2_   1312
#define NTOT  (B_ * N_)        // 131072
#define ETOT  (B_ * E_)        // 2097152
#define N2TOT (B_ * K1_)       // 104896
#define NCLS  6
#define PB_   8                // pool blocks per graph (index-partitioned)
#define CHUNKS_ 16             // dst-chunks per graph
#define SLICES_ 16             // edge slices per graph in k_bucket
#define BCAP  3072             // bucket capacity (= SLICES_*REG_)
#define REG_  192              // per-slice region (mean 128, sd ~11 -> +5.8 sigma)

typedef short bf8 __attribute__((ext_vector_type(8)));
typedef float f4  __attribute__((ext_vector_type(4)));

static __device__ __forceinline__ float2 bf2f(unsigned u) {
    float2 r;
    r.x = __uint_as_float(u << 16);
    r.y = __uint_as_float(u & 0xFFFF0000u);
    return r;
}
static __device__ __forceinline__ unsigned f2bf(float a, float b) {
    __hip_bfloat162 h = __float22bfloat162_rn(make_float2(a, b));
    unsigned u;
    __builtin_memcpy(&u, &h, 4);
    return u;
}
static __device__ __forceinline__ unsigned short f2bf_rn(float v) {
    unsigned u = __float_as_uint(v);
    return (unsigned short)((u + 0x7FFFu + ((u >> 16) & 1u)) >> 16);
}
static __device__ __forceinline__ unsigned long long mk_key(float s, int i) {
    unsigned u = __float_as_uint(s);
    u = (u & 0x80000000u) ? ~u : (u | 0x80000000u);
    return ((unsigned long long)u << 11) | (unsigned long long)(2047 - i);
}

// ---------------- bucket edges by (graph, dst-chunk) into slice-owned regions --------------
template<int STAGE>
__launch_bounds__(256)
__global__ void k_bucket(const int* src, const int* dst, const int* remap,
                         int* bcnt, unsigned int* blist) {
    const int LSTR = (STAGE == 1) ? 128 : 103;
    __shared__ unsigned int lb[CHUNKS_][REG_];
    __shared__ int lc[CHUNKS_];
    __shared__ int rm[N_];                     // stage2 only
    int b = blockIdx.x;
    int g = b & 63, slice = b >> 6;
    int tid = threadIdx.x;
    if (tid < CHUNKS_) lc[tid] = 0;
    if (STAGE == 2)
        for (int i = tid; i < N_; i += 256) rm[i] = remap[g * N_ + i];
    __syncthreads();
    const int ESL = E_ / SLICES_;              // 2048
    const int* sp = src + (size_t)g * E_ + slice * ESL;
    const int* dp = dst + (size_t)g * E_ + slice * ESL;
    int gbase = g * ((STAGE == 1) ? N_ : K1_);
    for (int e = tid * 4; e < ESL; e += 1024) {
        int4 ss = *(const int4*)&sp[e];
        int4 dd = *(const int4*)&dp[e];
#pragma unroll
        for (int t = 0; t < 4; t++) {
            int s = (&ss.x)[t], d = (&dd.x)[t];
            if (STAGE == 2) {
                s = rm[s & (N_ - 1)]; d = rm[d & (N_ - 1)];
                if ((s | d) < 0) continue;     // edge touches a dropped node
                s -= gbase; d -= gbase;
            } else {
                s &= (N_ - 1); d &= (N_ - 1);
            }
            int ch = d / LSTR;
            int dl = d - ch * LSTR;
            int p = atomicAdd(&lc[ch], 1);
            if (p < REG_) lb[ch][p] = ((unsigned)dl << 12) | (unsigned)s;
        }
    }
    __syncthreads();
    for (int ch = 0; ch < CHUNKS_; ch++) {
        int n = min(lc[ch], REG_);
        unsigned int* out = blist + (size_t)(g * CHUNKS_ + ch) * BCAP + slice * REG_;
        for (int i = tid; i < n; i += 256) out[i] = lb[ch][i];
    }
    if (tid < CHUNKS_) bcnt[(g * SLICES_ + slice) * CHUNKS_ + tid] = min(lc[tid], REG_);
}

// ---------------- counting-sort -> in-place compact CSR (pre-shifted) + ninfo + prescale ----
template<int STAGE>
__launch_bounds__(256)
__global__ void k_sort(const int* bcnt, unsigned int* blist,
                       const float* xf, const unsigned int* xg,
                       unsigned int* xb, int* ninfo) {
    const int NL   = (STAGE == 1) ? N_ : K1_;
    const int LSTR = (STAGE == 1) ? 128 : 103;
    __shared__ int cnt[128], st[128], cur[128], cnt_s[SLICES_], stot[2];
    __shared__ float rsqv[128];
    __shared__ unsigned short sorted[BCAP];
    int b = blockIdx.x;
    int g = b & 63, ch = b >> 6;
    int tid = threadIdx.x;
    if (tid < 128) { cnt[tid] = 0; cur[tid] = 0; }
    if (tid < SLICES_) cnt_s[tid] = bcnt[(g * SLICES_ + tid) * CHUNKS_ + ch];
    __syncthreads();
    size_t bb = (size_t)(g * CHUNKS_ + ch) * BCAP;
    const unsigned int* bl = blist + bb;
    const int TOT = SLICES_ * REG_;            // 3072
    for (int i = tid; i < TOT; i += 256) {
        int s = i / REG_, j = i - s * REG_;
        if (j < cnt_s[s]) atomicAdd(&cnt[bl[i] >> 12], 1);
    }
    __syncthreads();
    if (tid < 128) {
        int v = cnt[tid];
        int l64 = tid & 63;
#pragma unroll
        for (int o = 1; o < 64; o <<= 1) {
            int t = __shfl_up(v, o);
            if (l64 >= o) v += t;
        }
        st[tid] = v;
        if (l64 == 63) stot[tid >> 6] = v;
    }
    __syncthreads();
    if (tid >= 64 && tid < 128) st[tid] += stot[0];
    __syncthreads();
    for (int i = tid; i < TOT; i += 256) {
        int s = i / REG_, j = i - s * REG_;
        if (j < cnt_s[s]) {
            unsigned pk = bl[i];
            int dl = (int)(pk >> 12);
            int p = st[dl] - cnt[dl] + atomicAdd(&cur[dl], 1);
            sorted[p] = (unsigned short)(pk & 0xFFFu);
        }
    }
    __syncthreads();
    int n = st[127];
    for (int i = tid; i < n; i += 256) blist[bb + i] = ((unsigned int)sorted[i]) << 5;
    int lo = ch * LSTR;
    int nloc = min(LSTR, NL - lo);
    int gbase = g * NL;
    if (tid < nloc) {
        int node = gbase + lo + tid;
        int c = cnt[tid];
        int start = (int)bb + st[tid] - c;
        ninfo[node] = (start << 8) | min(c, 255);
        rsqv[tid] = rsqrtf((float)(c + 1));
    }
    __syncthreads();
    for (int idx = tid; idx < nloc * 32; idx += 256) {
        int nl = idx >> 5, f2 = idx & 31;
        int node = gbase + lo + nl;
        float sc = rsqv[nl];
        float2 v;
        if (STAGE == 1) v = ((const float2*)xf)[(size_t)node * 32 + f2];
        else            v = bf2f(xg[(size_t)node * 32 + f2]);
        xb[(size_t)node * 32 + f2] = f2bf(v.x * sc, v.y * sc);
    }
}

// ---------------- gather-aggregate over pre-scaled bf16 rows (R14-proven form) --------------
template<bool GATE>
__launch_bounds__(256)
__global__ void k_agg(const unsigned int* xb, const int* ninfo, const unsigned int* csr,
                      float* y) {
    int b = blockIdx.x;
    int xcd = b & 7, r = b >> 3;
    int graph, local;
    if (GATE) {
        graph = xcd * 8 + r / 410;            // ceil(1639/4)=410 blocks/graph
        local = (r % 410) * 4 + (threadIdx.x >> 6);
        if (local >= K1_) return;
    } else {
        graph = xcd * 8 + (r >> 9);           // 512 blocks/graph
        local = (r & 511) * 4 + (threadIdx.x >> 6);
    }
    const int NL = GATE ? K1_ : N_;
    int node = graph * NL + local;
    int lane = threadIdx.x & 63;
    int half = lane >> 5;
    int fpos = lane & 31;
    int ni = ninfo[node];
    int cnt = ni & 255, base = ni >> 8;
    float rd = rsqrtf((float)(cnt + 1));
    float ax = 0.f, ay = 0.f, bx = 0.f, by = 0.f;
    float cx = 0.f, cy = 0.f, dx = 0.f, dy = 0.f;
    int gbase32 = graph * NL * 32;
    for (int chunk = 0; chunk < cnt; chunk += 64) {
        int nch = min(64, cnt - chunk);
        int sv = 0;
        if (lane < nch) sv = gbase32 + (int)csr[base + chunk + lane];
        int i = 0;
        for (; i + 8 <= nch; i += 8) {
            int s0 = __shfl(sv, i + half),     s1 = __shfl(sv, i + 2 + half),
                s2 = __shfl(sv, i + 4 + half), s3 = __shfl(sv, i + 6 + half);
            unsigned u0 = xb[(size_t)(s0 + fpos)];
            unsigned u1 = xb[(size_t)(s1 + fpos)];
            unsigned u2 = xb[(size_t)(s2 + fpos)];
            unsigned u3 = xb[(size_t)(s3 + fpos)];
            float2 f0 = bf2f(u0), f1 = bf2f(u1), f2 = bf2f(u2), f3 = bf2f(u3);
            ax += f0.x; ay += f0.y;
            bx += f1.x; by += f1.y;
            cx += f2.x; cy += f2.y;
            dx += f3.x; dy += f3.y;
        }
        for (; i + 4 <= nch; i += 4) {
            int s0 = __shfl(sv, i + half), s1 = __shfl(sv, i + 2 + half);
            float2 f0 = bf2f(xb[(size_t)(s0 + fpos)]);
            float2 f1 = bf2f(xb[(size_t)(s1 + fpos)]);
            ax += f0.x; ay += f0.y;
            bx += f1.x; by += f1.y;
        }
        for (; i < nch; i += 2) {
            int idx = i + half;
            int s0 = __shfl(sv, idx & 63);
            float m = (idx < nch) ? 1.f : 0.f;
            float2 f0 = bf2f(xb[(size_t)(s0 + fpos)]);
            ax += f0.x * m; ay += f0.y * m;
        }
    }
    float sx = (ax + bx) + (cx + dx), sy = (ay + by) + (cy + dy);
    sx += __shfl(sx, lane ^ 32);
    sy += __shfl(sy, lane ^ 32);
    if (half == 0) {
        float2 fs = bf2f(xb[(size_t)node * 32 + fpos]);   // pre-scaled self row
        float2 o;
        o.x = (sx + fs.x) * rd;
        o.y = (sy + fs.y) * rd;
        ((float2*)y)[(size_t)node * 32 + fpos] = o;
    }
}

// ---------------- MFMA conv: conv = relu(y @ W + b), score = tanh(conv.p/||p||) ------------
__launch_bounds__(256)
__global__ void k_convrow(float* y, const float* W, const float* bias, const float* pvec,
                          float* score, int rows) {
    int wid  = threadIdx.x >> 6;
    int lane = threadIdx.x & 63;
    int rowbase = blockIdx.x * 64 + wid * 16;
    int q = lane >> 4, c = lane & 15;
    bf8 bh[2][4], blo[2][4];
#pragma unroll
    for (int ks = 0; ks < 2; ks++)
#pragma unroll
        for (int nt = 0; nt < 4; nt++) {
            bf8 h, l;
#pragma unroll
            for (int j = 0; j < 8; j++) {
                float wv = W[(ks * 32 + q * 8 + j) * 64 + nt * 16 + c];
                unsigned short hb = f2bf_rn(wv);
                h[j] = (short)hb;
                l[j] = (short)f2bf_rn(wv - __uint_as_float((unsigned)hb << 16));
            }
            bh[ks][nt] = h; blo[ks][nt] = l;
        }
    const float* yr = y + (size_t)(rowbase + c) * DIM_ + q * 8;
    bf8 ah[2], al[2];
#pragma unroll
    for (int ks = 0; ks < 2; ks++) {
        float4 v0 = *(const float4*)(yr + ks * 32);
        float4 v1 = *(const float4*)(yr + ks * 32 + 4);
        float vv[8] = {v0.x, v0.y, v0.z, v0.w, v1.x, v1.y, v1.z, v1.w};
        bf8 h, l;
#pragma unroll
        for (int j = 0; j < 8; j++) {
            unsigned short hb = f2bf_rn(vv[j]);
            h[j] = (short)hb;
            l[j] = (short)f2bf_rn(vv[j] - __uint_as_float((unsigned)hb << 16));
        }
        ah[ks] = h; al[ks] = l;
    }
    float pp = 0.f;
#pragma unroll
    for (int i = 0; i < DIM_; i++) pp += pvec[i] * pvec[i];
    float rpn = rsqrtf(pp);
    float dot[4] = {0.f, 0.f, 0.f, 0.f};
#pragma unroll
    for (int nt = 0; nt < 4; nt++) {
        f4 acc = {0.f, 0.f, 0.f, 0.f};
#pragma unroll
        for (int ks = 0; ks < 2; ks++) {
            acc = __builtin_amdgcn_mfma_f32_16x16x32_bf16(ah[ks], bh[ks][nt],  acc, 0, 0, 0);
            acc = __builtin_amdgcn_mfma_f32_16x16x32_bf16(ah[ks], blo[ks][nt], acc, 0, 0, 0);
            acc = __builtin_amdgcn_mfma_f32_16x16x32_bf16(al[ks], bh[ks][nt],  acc, 0, 0, 0);
        }
        float bcol = bias[nt * 16 + c];
        float pcol = pvec[nt * 16 + c];
        float st[4];
#pragma unroll
        for (int reg = 0; reg < 4; reg++) {
            float v = fmaxf(acc[reg] + bcol, 0.f);
            st[reg] = v;
            dot[reg] += v * pcol;
        }
#pragma unroll
        for (int reg = 0; reg < 4; reg++)
            y[(size_t)(rowbase + q * 4 + reg) * DIM_ + nt * 16 + c] = st[reg];
    }
#pragma unroll
    for (int m = 1; m < 16; m <<= 1) {
#pragma unroll
        for (int reg = 0; reg < 4; reg++) dot[reg] += __shfl_xor(dot[reg], m);
    }
    if (c == 0) {
#pragma unroll
        for (int reg = 0; reg < 4; reg++)
            score[rowbase + q * 4 + reg] = tanhf(dot[reg] * rpn);
    }
    (void)rows;
}

// ---------------- exact K-th-largest key per graph (6-pass radix, R14-proven) --------------
template<int STAGE>
__launch_bounds__(256)
__global__ void k_thresh(const float* score, unsigned long long* thresh) {
    const int Nin = (STAGE == 1) ? N_ : K1_;
    const int K   = (STAGE == 1) ? K1_ : K2_;
    __shared__ unsigned long long keys[N_];
    __shared__ int bins[256], wsum[4];
    __shared__ unsigned long long s_prefix;
    __shared__ int s_need;
    int g = blockIdx.x, tid = threadIdx.x;
    int l64 = tid & 63, wid = tid >> 6;
    const float* sg = score + (size_t)g * Nin;
    for (int i = tid; i < Nin; i += 256) keys[i] = mk_key(sg[i], i);
    if (tid == 0) { s_need = K; s_prefix = 0ull; }
    __syncthreads();
    for (int shift = 40; shift >= 0; shift -= 8) {
        bins[tid] = 0;
        __syncthreads();
        unsigned long long pref = s_prefix;
        int need = s_need;
        int hi = shift + 8;
        for (int i = tid; i < Nin; i += 256) {
            unsigned long long k = keys[i];
            if ((k >> hi) == pref) atomicAdd(&bins[(int)((k >> shift) & 255)], 1);
        }
        __syncthreads();
        int mine = bins[tid];
        int v = mine;
#pragma unroll
        for (int o = 1; o < 64; o <<= 1) {     // wave suffix scan
            int t = __shfl_down(v, o);
            if (l64 + o < 64) v += t;
        }
        if (l64 == 0) wsum[wid] = v;
        __syncthreads();
        for (int w = wid + 1; w < 4; w++) v += wsum[w];
        int nxt = v - mine;
        if (v >= need && nxt < need) {         // exactly one tid matches
            s_prefix = (pref << 8) | (unsigned long long)tid;
            s_need = need - nxt;
        }
        __syncthreads();
    }
    if (tid == 0) thresh[g] = s_prefix;
}

// ---------------- pool (+rank/newid/xg in stage1), PB_ blocks/graph, threshold handoff ------
template<int STAGE>
__launch_bounds__(256)
__global__ void k_pool(const float* score, const float* conv, const unsigned long long* thresh,
                       int* new_id, unsigned int* xg, float* part) {
    const int Nin = (STAGE == 1) ? N_ : K1_;
    const int RNG = (STAGE == 1) ? (N_ / PB_) : ((K1_ + PB_ - 1) / PB_);  // 256 / 205
    __shared__ int rnk[256];
    __shared__ unsigned char keepf[256];
    __shared__ int wsum[4], s_base[4];
    __shared__ float rmx[4][64], rsm[4][64];
    int b = blockIdx.x;
    int g = b & 63, pb = b >> 6;
    int tid = threadIdx.x;
    int l64 = tid & 63, wid = tid >> 6;
    const float* sg = score + (size_t)g * Nin;
    unsigned long long T = thresh[g];
    int R0 = pb * RNG;
    int R1 = min(R0 + RNG, Nin);
    if (STAGE == 1) {
        // base = # kept in [0, R0): streamed count (L2-hot score)
        int cb = 0;
        for (int i = tid; i < R0; i += 256) cb += (mk_key(sg[i], i) >= T) ? 1 : 0;
#pragma unroll
        for (int o = 32; o; o >>= 1) cb += __shfl_down(cb, o);
        if (l64 == 0) s_base[wid] = cb;
        // this block's range: one index per thread
        int i = R0 + tid;
        int keep = (i < R1 && mk_key(sg[i], i) >= T) ? 1 : 0;
        keepf[tid] = (unsigned char)keep;
        int v = keep;
#pragma unroll
        for (int o = 1; o < 64; o <<= 1) {     // inclusive wave scan (index order)
            int t = __shfl_up(v, o);
            if (l64 >= o) v += t;
        }
        if (l64 == 63) wsum[wid] = v;
        __syncthreads();
        int base = s_base[0] + s_base[1] + s_base[2] + s_base[3];
        int wbase = 0;
        for (int w = 0; w < wid; w++) wbase += wsum[w];
        int r = base + wbase + v - keep;       // exclusive rank
        rnk[tid] = r;
        if (i < Nin) new_id[g * N_ + i] = keep ? (g * K1_ + r) : -1;
    } else {
        int i = R0 + tid;
        keepf[tid] = (unsigned char)((i < R1 && mk_key(sg[i], i) >= T) ? 1 : 0);
    }
    __syncthreads();
    // ---- pool this block's range; wave per node, lane == feature ----
    float mx = -3.402823466e38f, sm = 0.f;
    for (int i = R0 + wid; i < R1; i += 4) {
        if (!keepf[i - R0]) continue;          // wave-uniform
        float val = sg[i];
        float v = conv[(size_t)(g * Nin + i) * DIM_ + l64] * val;
        mx = fmaxf(mx, v);
        sm += v;
        if (STAGE == 1) {
            unsigned pk = f2bf(v, __shfl_xor(v, 1));
            if (!(l64 & 1)) xg[(size_t)(g * K1_ + rnk[i - R0]) * 32 + (l64 >> 1)] = pk;
        }
    }
    rmx[wid][l64] = mx; rsm[wid][l64] = sm;
    __syncthreads();
    if (wid == 0) {
        mx = fmaxf(fmaxf(rmx[0][l64], rmx[1][l64]), fmaxf(rmx[2][l64], rmx[3][l64]));
        sm = rsm[0][l64] + rsm[1][l64] + rsm[2][l64] + rsm[3][l64];
        part[((size_t)(g * PB_ + pb) * 2 + 0) * 64 + l64] = mx;
        part[((size_t)(g * PB_ + pb) * 2 + 1) * 64 + l64] = sm;
    }
}

// ---------------- MLP head (combines both stages' partials) ----------------
__launch_bounds__(64)
__global__ void k_head(const float* part1, const float* part2,
                       const float* l1w, const float* l1b,
                       const float* l2w, const float* l2b, float* out) {
    __shared__ float h[128];
    __shared__ float h1[64];
    int g = blockIdx.x, t = threadIdx.x;
    float mx1 = -3.402823466e38f, sm1 = 0.f, mx2 = -3.402823466e38f, sm2 = 0.f;
#pragma unroll
    for (int c = 0; c < PB_; c++) {
        mx1 = fmaxf(mx1, part1[((size_t)(g * PB_ + c) * 2 + 0) * 64 + t]);
        sm1 += part1[((size_t)(g * PB_ + c) * 2 + 1) * 64 + t];
        mx2 = fmaxf(mx2, part2[((size_t)(g * PB_ + c) * 2 + 0) * 64 + t]);
        sm2 += part2[((size_t)(g * PB_ + c) * 2 + 1) * 64 + t];
    }
    h[t]      = mx1 + mx2;
    h[t + 64] = sm1 / (float)K1_ + sm2 / (float)K2_;
    __syncthreads();
    float acc = l1b[t];
#pragma unroll 8
    for (int i = 0; i < 128; i++) acc += h[i] * l1w[i * 64 + t];
    h1[t] = fmaxf(acc, 0.0f);
    __syncthreads();
    if (t < NCLS) {
        float o = l2b[t];
#pragma unroll
        for (int i = 0; i < 64; i++) o += h1[i] * l2w[i * NCLS + t];
        out[g * NCLS + t] = o;
    }
}

extern "C" void kernel_launch(void* const* d_in, const int* in_sizes, int n_in,
                              void* d_out, int out_size, void* d_ws, size_t ws_size,
                              hipStream_t stream) {
    const float* x   = (const float*)d_in[0];
    const int*   ei  = (const int*)d_in[1];
    const int*   src = ei;
    const int*   dst = ei + ETOT;
    const float* W1  = (const float*)d_in[3];
    const float* b1  = (const float*)d_in[4];
    const float* p1  = (const float*)d_in[5];
    const float* W2  = (const float*)d_in[6];
    const float* b2  = (const float*)d_in[7];
    const float* p2  = (const float*)d_in[8];
    const float* l1w = (const float*)d_in[9];
    const float* l1b = (const float*)d_in[10];
    const float* l2w = (const float*)d_in[11];
    const float* l2b = (const float*)d_in[12];
    (void)in_sizes; (void)n_in; (void)out_size; (void)ws_size;

    // workspace layout (~92 MB); xg aliases bufB (dead until agg2 writes it)
    char* ws = (char*)d_ws;
    size_t off = 0;
    auto alloc = [&](size_t bytes) -> void* {
        void* p = ws + off;
        off = (off + bytes + 255) & ~(size_t)255;
        return p;
    };
    float*              bufA   = (float*)             alloc((size_t)NTOT  * DIM_ * 4);
    float*              bufB   = (float*)             alloc((size_t)N2TOT * DIM_ * 4);
    unsigned int*       blist  = (unsigned int*)      alloc((size_t)B_ * CHUNKS_ * BCAP * 4);
    unsigned int*       xb     = (unsigned int*)      alloc((size_t)NTOT * 32 * 4);
    int*                bcnt   = (int*)               alloc((size_t)B_ * SLICES_ * CHUNKS_ * 4);
    int*                ninfo  = (int*)               alloc((size_t)NTOT * 4);
    float*              score  = (float*)             alloc((size_t)NTOT * 4);
    int*                newid  = (int*)               alloc((size_t)NTOT * 4);
    unsigned long long* thr    = (unsigned long long*)alloc((size_t)B_ * 8);
    float*              part1  = (float*)             alloc((size_t)B_ * PB_ * 128 * 4);
    float*              part2  = (float*)             alloc((size_t)B_ * PB_ * 128 * 4);
    unsigned int*       xg     = (unsigned int*)bufB;   // alias

    // ---- stage 1 ----
    k_bucket<1><<<B_ * SLICES_, 256, 0, stream>>>(src, dst, nullptr, bcnt, blist);
    k_sort<1><<<B_ * CHUNKS_, 256, 0, stream>>>(bcnt, blist, x, nullptr, xb, ninfo);
    k_agg<false><<<NTOT / 4, 256, 0, stream>>>(xb, ninfo, blist, bufA);
    k_convrow<<<NTOT / 64, 256, 0, stream>>>(bufA, W1, b1, p1, score, NTOT);
    k_thresh<1><<<B_, 256, 0, stream>>>(score, thr);
    k_pool<1><<<B_ * PB_, 256, 0, stream>>>(score, bufA, thr, newid, xg, part1);

    // ---- stage 2 ----
    k_bucket<2><<<B_ * SLICES_, 256, 0, stream>>>(src, dst, newid, bcnt, blist);
    k_sort<2><<<B_ * CHUNKS_, 256, 0, stream>>>(bcnt, blist, nullptr, xg, xb, ninfo);
    k_agg<true><<<410 * B_, 256, 0, stream>>>(xb, ninfo, blist, bufB);
    k_convrow<<<N2TOT / 64, 256, 0, stream>>>(bufB, W2, b2, p2, score, N2TOT);
    k_thresh<2><<<B_, 256, 0, stream>>>(score, thr);
    k_pool<2><<<B_ * PB_, 256, 0, stream>>>(score, bufB, thr, nullptr, nullptr, part2);

    // ---- head (combines both stages' partials) ----
    k_head<<<B_, 64, 0, stream>>>(part1, part2, l1w, l1b, l2w, l2b, (float*)d_out);
}

// Round 20
// 317.818 us; speedup vs baseline: 1.0621x; 1.0621x over previous
//
#include <hip/hip_runtime.h>
#include <hip/hip_bf16.h>
#include <cstdint>
#include <cstddef>

#define B_    64
#define N_    2048
#define E_    32768            // edges per graph
#define DIM_  64
#define K1_   1639
#define K2_   1312
#define NTOT  (B_ * N_)        // 131072
#define ETOT  (B_ * E_)        // 2097152
#define N2TOT (B_ * K1_)       // 104896
#define NCLS  6
#define PB_   8                // pool blocks per graph (index-partitioned)
#define CHUNKS_ 16             // dst-chunks per graph
#define SLICES_ 16             // edge slices per graph in k_bucket
#define BCAP  3072             // bucket capacity (= SLICES_*REG_)
#define REG_  192              // per-slice region (mean 128, sd ~11 -> +5.8 sigma)

typedef short bf8 __attribute__((ext_vector_type(8)));
typedef float f4  __attribute__((ext_vector_type(4)));

static __device__ __forceinline__ float2 bf2f(unsigned u) {
    float2 r;
    r.x = __uint_as_float(u << 16);
    r.y = __uint_as_float(u & 0xFFFF0000u);
    return r;
}
static __device__ __forceinline__ unsigned f2bf(float a, float b) {
    __hip_bfloat162 h = __float22bfloat162_rn(make_float2(a, b));
    unsigned u;
    __builtin_memcpy(&u, &h, 4);
    return u;
}
static __device__ __forceinline__ unsigned short f2bf_rn(float v) {
    unsigned u = __float_as_uint(v);
    return (unsigned short)((u + 0x7FFFu + ((u >> 16) & 1u)) >> 16);
}
static __device__ __forceinline__ unsigned long long mk_key(float s, int i) {
    unsigned u = __float_as_uint(s);
    u = (u & 0x80000000u) ? ~u : (u | 0x80000000u);
    return ((unsigned long long)u << 11) | (unsigned long long)(2047 - i);
}

// ---------------- bucket edges by (graph, dst-chunk) into slice-owned regions --------------
template<int STAGE>
__launch_bounds__(256)
__global__ void k_bucket(const int* src, const int* dst, const int* remap,
                         int* bcnt, unsigned int* blist) {
    const int LSTR = (STAGE == 1) ? 128 : 103;
    __shared__ unsigned int lb[CHUNKS_][REG_];
    __shared__ int lc[CHUNKS_];
    __shared__ int rm[N_];                     // stage2 only
    int b = blockIdx.x;
    int g = b & 63, slice = b >> 6;
    int tid = threadIdx.x;
    if (tid < CHUNKS_) lc[tid] = 0;
    if (STAGE == 2)
        for (int i = tid; i < N_; i += 256) rm[i] = remap[g * N_ + i];
    __syncthreads();
    const int ESL = E_ / SLICES_;              // 2048
    const int* sp = src + (size_t)g * E_ + slice * ESL;
    const int* dp = dst + (size_t)g * E_ + slice * ESL;
    int gbase = g * ((STAGE == 1) ? N_ : K1_);
    for (int e = tid * 4; e < ESL; e += 1024) {
        int4 ss = *(const int4*)&sp[e];
        int4 dd = *(const int4*)&dp[e];
#pragma unroll
        for (int t = 0; t < 4; t++) {
            int s = (&ss.x)[t], d = (&dd.x)[t];
            if (STAGE == 2) {
                s = rm[s & (N_ - 1)]; d = rm[d & (N_ - 1)];
                if ((s | d) < 0) continue;     // edge touches a dropped node
                s -= gbase; d -= gbase;
            } else {
                s &= (N_ - 1); d &= (N_ - 1);
            }
            int ch = d / LSTR;
            int dl = d - ch * LSTR;
            int p = atomicAdd(&lc[ch], 1);
            if (p < REG_) lb[ch][p] = ((unsigned)dl << 12) | (unsigned)s;
        }
    }
    __syncthreads();
    for (int ch = 0; ch < CHUNKS_; ch++) {
        int n = min(lc[ch], REG_);
        unsigned int* out = blist + (size_t)(g * CHUNKS_ + ch) * BCAP + slice * REG_;
        for (int i = tid; i < n; i += 256) out[i] = lb[ch][i];
    }
    if (tid < CHUNKS_) bcnt[(g * SLICES_ + slice) * CHUNKS_ + tid] = min(lc[tid], REG_);
}

// ---------------- counting-sort -> in-place compact CSR (pre-shifted) + ninfo + prescale ----
template<int STAGE>
__launch_bounds__(256)
__global__ void k_sort(const int* bcnt, unsigned int* blist,
                       const float* xf, const unsigned int* xg,
                       unsigned int* xb, int* ninfo) {
    const int NL   = (STAGE == 1) ? N_ : K1_;
    const int LSTR = (STAGE == 1) ? 128 : 103;
    __shared__ int cnt[128], st[128], cur[128], cnt_s[SLICES_], stot[2];
    __shared__ float rsqv[128];
    __shared__ unsigned short sorted[BCAP];
    int b = blockIdx.x;
    int g = b & 63, ch = b >> 6;
    int tid = threadIdx.x;
    if (tid < 128) { cnt[tid] = 0; cur[tid] = 0; }
    if (tid < SLICES_) cnt_s[tid] = bcnt[(g * SLICES_ + tid) * CHUNKS_ + ch];
    __syncthreads();
    size_t bb = (size_t)(g * CHUNKS_ + ch) * BCAP;
    const unsigned int* bl = blist + bb;
    const int TOT = SLICES_ * REG_;            // 3072
    for (int i = tid; i < TOT; i += 256) {
        int s = i / REG_, j = i - s * REG_;
        if (j < cnt_s[s]) atomicAdd(&cnt[bl[i] >> 12], 1);
    }
    __syncthreads();
    if (tid < 128) {
        int v = cnt[tid];
        int l64 = tid & 63;
#pragma unroll
        for (int o = 1; o < 64; o <<= 1) {
            int t = __shfl_up(v, o);
            if (l64 >= o) v += t;
        }
        st[tid] = v;
        if (l64 == 63) stot[tid >> 6] = v;
    }
    __syncthreads();
    if (tid >= 64 && tid < 128) st[tid] += stot[0];
    __syncthreads();
    for (int i = tid; i < TOT; i += 256) {
        int s = i / REG_, j = i - s * REG_;
        if (j < cnt_s[s]) {
            unsigned pk = bl[i];
            int dl = (int)(pk >> 12);
            int p = st[dl] - cnt[dl] + atomicAdd(&cur[dl], 1);
            sorted[p] = (unsigned short)(pk & 0xFFFu);
        }
    }
    __syncthreads();
    int n = st[127];
    for (int i = tid; i < n; i += 256) blist[bb + i] = ((unsigned int)sorted[i]) << 5;
    int lo = ch * LSTR;
    int nloc = min(LSTR, NL - lo);
    int gbase = g * NL;
    if (tid < nloc) {
        int node = gbase + lo + tid;
        int c = cnt[tid];
        int start = (int)bb + st[tid] - c;
        ninfo[node] = (start << 8) | min(c, 255);
        rsqv[tid] = rsqrtf((float)(c + 1));
    }
    __syncthreads();
    for (int idx = tid; idx < nloc * 32; idx += 256) {
        int nl = idx >> 5, f2 = idx & 31;
        int node = gbase + lo + nl;
        float sc = rsqv[nl];
        float2 v;
        if (STAGE == 1) v = ((const float2*)xf)[(size_t)node * 32 + f2];
        else            v = bf2f(xg[(size_t)node * 32 + f2]);
        xb[(size_t)node * 32 + f2] = f2bf(v.x * sc, v.y * sc);
    }
}

// ---------------- gather-aggregate: TWO nodes per wave (independent half-wave chains) -------
// Lanes 0-31 own node A, 32-63 own node B. Per edge: 32 lanes x 4B = one 128B bf16 row;
// 4-deep unroll -> 8 gather loads in flight per wave (2 chains). 8 nodes per block.
template<bool GATE>
__launch_bounds__(256)
__global__ void k_agg(const unsigned int* xb, const int* ninfo, const unsigned int* csr,
                      float* y) {
    int b = blockIdx.x;
    int xcd = b & 7, r = b >> 3;
    int wid = threadIdx.x >> 6, lane = threadIdx.x & 63;
    int half = lane >> 5;                      // which node of the wave-pair
    int sub = wid * 2 + half;                  // node index within block, 0..7
    int graph, local;
    if (GATE) {
        graph = xcd * 8 + r / 205;             // ceil(1639/8)=205 blocks/graph
        local = (r % 205) * 8 + sub;
        if (local >= K1_) return;
    } else {
        graph = xcd * 8 + (r >> 8);            // 256 blocks/graph
        local = (r & 255) * 8 + sub;
    }
    const int NL = GATE ? K1_ : N_;
    int node = graph * NL + local;
    int l32 = lane & 31;                       // feature-pair slot (2 features)
    int hbase = half << 5;                     // shfl source base for this half
    int ni = ninfo[node];
    int cnt = ni & 255, base = ni >> 8;
    float rd = rsqrtf((float)(cnt + 1));
    float a0x = 0.f, a0y = 0.f, a1x = 0.f, a1y = 0.f;
    float a2x = 0.f, a2y = 0.f, a3x = 0.f, a3y = 0.f;
    int gbase32 = graph * NL * 32;
    for (int chunk = 0; chunk < cnt; chunk += 32) {
        int nch = min(32, cnt - chunk);
        int sv = 0;
        if (l32 < nch) sv = gbase32 + (int)csr[base + chunk + l32];   // element offset
        int i = 0;
        for (; i + 4 <= nch; i += 4) {
            int e0 = __shfl(sv, hbase + i);
            int e1 = __shfl(sv, hbase + i + 1);
            int e2 = __shfl(sv, hbase + i + 2);
            int e3 = __shfl(sv, hbase + i + 3);
            unsigned u0 = xb[(size_t)(e0 + l32)];
            unsigned u1 = xb[(size_t)(e1 + l32)];
            unsigned u2 = xb[(size_t)(e2 + l32)];
            unsigned u3 = xb[(size_t)(e3 + l32)];
            float2 f0 = bf2f(u0), f1 = bf2f(u1), f2 = bf2f(u2), f3 = bf2f(u3);
            a0x += f0.x; a0y += f0.y;
            a1x += f1.x; a1y += f1.y;
            a2x += f2.x; a2y += f2.y;
            a3x += f3.x; a3y += f3.y;
        }
        for (; i < nch; i++) {
            int e0 = __shfl(sv, hbase + i);
            float2 f0 = bf2f(xb[(size_t)(e0 + l32)]);
            a0x += f0.x; a0y += f0.y;
        }
    }
    float sx = (a0x + a1x) + (a2x + a3x);
    float sy = (a0y + a1y) + (a2y + a3y);
    float2 fs = bf2f(xb[(size_t)node * 32 + l32]);   // pre-scaled self row
    float2 o;
    o.x = (sx + fs.x) * rd;
    o.y = (sy + fs.y) * rd;
    ((float2*)y)[(size_t)node * 32 + l32] = o;
}

// ---------------- MFMA conv: conv = relu(y @ W + b), score = tanh(conv.p/||p||) ------------
__launch_bounds__(256)
__global__ void k_convrow(float* y, const float* W, const float* bias, const float* pvec,
                          float* score, int rows) {
    int wid  = threadIdx.x >> 6;
    int lane = threadIdx.x & 63;
    int rowbase = blockIdx.x * 64 + wid * 16;
    int q = lane >> 4, c = lane & 15;
    bf8 bh[2][4], blo[2][4];
#pragma unroll
    for (int ks = 0; ks < 2; ks++)
#pragma unroll
        for (int nt = 0; nt < 4; nt++) {
            bf8 h, l;
#pragma unroll
            for (int j = 0; j < 8; j++) {
                float wv = W[(ks * 32 + q * 8 + j) * 64 + nt * 16 + c];
                unsigned short hb = f2bf_rn(wv);
                h[j] = (short)hb;
                l[j] = (short)f2bf_rn(wv - __uint_as_float((unsigned)hb << 16));
            }
            bh[ks][nt] = h; blo[ks][nt] = l;
        }
    const float* yr = y + (size_t)(rowbase + c) * DIM_ + q * 8;
    bf8 ah[2], al[2];
#pragma unroll
    for (int ks = 0; ks < 2; ks++) {
        float4 v0 = *(const float4*)(yr + ks * 32);
        float4 v1 = *(const float4*)(yr + ks * 32 + 4);
        float vv[8] = {v0.x, v0.y, v0.z, v0.w, v1.x, v1.y, v1.z, v1.w};
        bf8 h, l;
#pragma unroll
        for (int j = 0; j < 8; j++) {
            unsigned short hb = f2bf_rn(vv[j]);
            h[j] = (short)hb;
            l[j] = (short)f2bf_rn(vv[j] - __uint_as_float((unsigned)hb << 16));
        }
        ah[ks] = h; al[ks] = l;
    }
    float pp = 0.f;
#pragma unroll
    for (int i = 0; i < DIM_; i++) pp += pvec[i] * pvec[i];
    float rpn = rsqrtf(pp);
    float dot[4] = {0.f, 0.f, 0.f, 0.f};
#pragma unroll
    for (int nt = 0; nt < 4; nt++) {
        f4 acc = {0.f, 0.f, 0.f, 0.f};
#pragma unroll
        for (int ks = 0; ks < 2; ks++) {
            acc = __builtin_amdgcn_mfma_f32_16x16x32_bf16(ah[ks], bh[ks][nt],  acc, 0, 0, 0);
            acc = __builtin_amdgcn_mfma_f32_16x16x32_bf16(ah[ks], blo[ks][nt], acc, 0, 0, 0);
            acc = __builtin_amdgcn_mfma_f32_16x16x32_bf16(al[ks], bh[ks][nt],  acc, 0, 0, 0);
        }
        float bcol = bias[nt * 16 + c];
        float pcol = pvec[nt * 16 + c];
        float st[4];
#pragma unroll
        for (int reg = 0; reg < 4; reg++) {
            float v = fmaxf(acc[reg] + bcol, 0.f);
            st[reg] = v;
            dot[reg] += v * pcol;
        }
#pragma unroll
        for (int reg = 0; reg < 4; reg++)
            y[(size_t)(rowbase + q * 4 + reg) * DIM_ + nt * 16 + c] = st[reg];
    }
#pragma unroll
    for (int m = 1; m < 16; m <<= 1) {
#pragma unroll
        for (int reg = 0; reg < 4; reg++) dot[reg] += __shfl_xor(dot[reg], m);
    }
    if (c == 0) {
#pragma unroll
        for (int reg = 0; reg < 4; reg++)
            score[rowbase + q * 4 + reg] = tanhf(dot[reg] * rpn);
    }
    (void)rows;
}

// ---------------- exact K-th-largest key per graph (6-pass radix) --------------
template<int STAGE>
__launch_bounds__(256)
__global__ void k_thresh(const float* score, unsigned long long* thresh) {
    const int Nin = (STAGE == 1) ? N_ : K1_;
    const int K   = (STAGE == 1) ? K1_ : K2_;
    __shared__ unsigned long long keys[N_];
    __shared__ int bins[256], wsum[4];
    __shared__ unsigned long long s_prefix;
    __shared__ int s_need;
    int g = blockIdx.x, tid = threadIdx.x;
    int l64 = tid & 63, wid = tid >> 6;
    const float* sg = score + (size_t)g * Nin;
    for (int i = tid; i < Nin; i += 256) keys[i] = mk_key(sg[i], i);
    if (tid == 0) { s_need = K; s_prefix = 0ull; }
    __syncthreads();
    for (int shift = 40; shift >= 0; shift -= 8) {
        bins[tid] = 0;
        __syncthreads();
        unsigned long long pref = s_prefix;
        int need = s_need;
        int hi = shift + 8;
        for (int i = tid; i < Nin; i += 256) {
            unsigned long long k = keys[i];
            if ((k >> hi) == pref) atomicAdd(&bins[(int)((k >> shift) & 255)], 1);
        }
        __syncthreads();
        int mine = bins[tid];
        int v = mine;
#pragma unroll
        for (int o = 1; o < 64; o <<= 1) {     // wave suffix scan
            int t = __shfl_down(v, o);
            if (l64 + o < 64) v += t;
        }
        if (l64 == 0) wsum[wid] = v;
        __syncthreads();
        for (int w = wid + 1; w < 4; w++) v += wsum[w];
        int nxt = v - mine;
        if (v >= need && nxt < need) {         // exactly one tid matches
            s_prefix = (pref << 8) | (unsigned long long)tid;
            s_need = need - nxt;
        }
        __syncthreads();
    }
    if (tid == 0) thresh[g] = s_prefix;
}

// ---------------- pool (+rank/newid/xg in stage1), PB_ blocks/graph, threshold handoff ------
template<int STAGE>
__launch_bounds__(256)
__global__ void k_pool(const float* score, const float* conv, const unsigned long long* thresh,
                       int* new_id, unsigned int* xg, float* part) {
    const int Nin = (STAGE == 1) ? N_ : K1_;
    const int RNG = (STAGE == 1) ? (N_ / PB_) : ((K1_ + PB_ - 1) / PB_);  // 256 / 205
    __shared__ int rnk[256];
    __shared__ unsigned char keepf[256];
    __shared__ int wsum[4], s_base[4];
    __shared__ float rmx[4][64], rsm[4][64];
    int b = blockIdx.x;
    int g = b & 63, pb = b >> 6;
    int tid = threadIdx.x;
    int l64 = tid & 63, wid = tid >> 6;
    const float* sg = score + (size_t)g * Nin;
    unsigned long long T = thresh[g];
    int R0 = pb * RNG;
    int R1 = min(R0 + RNG, Nin);
    if (STAGE == 1) {
        int cb = 0;
        for (int i = tid; i < R0; i += 256) cb += (mk_key(sg[i], i) >= T) ? 1 : 0;
#pragma unroll
        for (int o = 32; o; o >>= 1) cb += __shfl_down(cb, o);
        if (l64 == 0) s_base[wid] = cb;
        int i = R0 + tid;
        int keep = (i < R1 && mk_key(sg[i], i) >= T) ? 1 : 0;
        keepf[tid] = (unsigned char)keep;
        int v = keep;
#pragma unroll
        for (int o = 1; o < 64; o <<= 1) {
            int t = __shfl_up(v, o);
            if (l64 >= o) v += t;
        }
        if (l64 == 63) wsum[wid] = v;
        __syncthreads();
        int base = s_base[0] + s_base[1] + s_base[2] + s_base[3];
        int wbase = 0;
        for (int w = 0; w < wid; w++) wbase += wsum[w];
        int r = base + wbase + v - keep;
        rnk[tid] = r;
        if (i < Nin) new_id[g * N_ + i] = keep ? (g * K1_ + r) : -1;
    } else {
        int i = R0 + tid;
        keepf[tid] = (unsigned char)((i < R1 && mk_key(sg[i], i) >= T) ? 1 : 0);
    }
    __syncthreads();
    float mx = -3.402823466e38f, sm = 0.f;
    for (int i = R0 + wid; i < R1; i += 4) {
        if (!keepf[i - R0]) continue;
        float val = sg[i];
        float v = conv[(size_t)(g * Nin + i) * DIM_ + l64] * val;
        mx = fmaxf(mx, v);
        sm += v;
        if (STAGE == 1) {
            unsigned pk = f2bf(v, __shfl_xor(v, 1));
            if (!(l64 & 1)) xg[(size_t)(g * K1_ + rnk[i - R0]) * 32 + (l64 >> 1)] = pk;
        }
    }
    rmx[wid][l64] = mx; rsm[wid][l64] = sm;
    __syncthreads();
    if (wid == 0) {
        mx = fmaxf(fmaxf(rmx[0][l64], rmx[1][l64]), fmaxf(rmx[2][l64], rmx[3][l64]));
        sm = rsm[0][l64] + rsm[1][l64] + rsm[2][l64] + rsm[3][l64];
        part[((size_t)(g * PB_ + pb) * 2 + 0) * 64 + l64] = mx;
        part[((size_t)(g * PB_ + pb) * 2 + 1) * 64 + l64] = sm;
    }
}

// ---------------- MLP head (combines both stages' partials) ----------------
__launch_bounds__(64)
__global__ void k_head(const float* part1, const float* part2,
                       const float* l1w, const float* l1b,
                       const float* l2w, const float* l2b, float* out) {
    __shared__ float h[128];
    __shared__ float h1[64];
    int g = blockIdx.x, t = threadIdx.x;
    float mx1 = -3.402823466e38f, sm1 = 0.f, mx2 = -3.402823466e38f, sm2 = 0.f;
#pragma unroll
    for (int c = 0; c < PB_; c++) {
        mx1 = fmaxf(mx1, part1[((size_t)(g * PB_ + c) * 2 + 0) * 64 + t]);
        sm1 += part1[((size_t)(g * PB_ + c) * 2 + 1) * 64 + t];
        mx2 = fmaxf(mx2, part2[((size_t)(g * PB_ + c) * 2 + 0) * 64 + t]);
        sm2 += part2[((size_t)(g * PB_ + c) * 2 + 1) * 64 + t];
    }
    h[t]      = mx1 + mx2;
    h[t + 64] = sm1 / (float)K1_ + sm2 / (float)K2_;
    __syncthreads();
    float acc = l1b[t];
#pragma unroll 8
    for (int i = 0; i < 128; i++) acc += h[i] * l1w[i * 64 + t];
    h1[t] = fmaxf(acc, 0.0f);
    __syncthreads();
    if (t < NCLS) {
        float o = l2b[t];
#pragma unroll
        for (int i = 0; i < 64; i++) o += h1[i] * l2w[i * NCLS + t];
        out[g * NCLS + t] = o;
    }
}

extern "C" void kernel_launch(void* const* d_in, const int* in_sizes, int n_in,
                              void* d_out, int out_size, void* d_ws, size_t ws_size,
                              hipStream_t stream) {
    const float* x   = (const float*)d_in[0];
    const int*   ei  = (const int*)d_in[1];
    const int*   src = ei;
    const int*   dst = ei + ETOT;
    const float* W1  = (const float*)d_in[3];
    const float* b1  = (const float*)d_in[4];
    const float* p1  = (const float*)d_in[5];
    const float* W2  = (const float*)d_in[6];
    const float* b2  = (const float*)d_in[7];
    const float* p2  = (const float*)d_in[8];
    const float* l1w = (const float*)d_in[9];
    const float* l1b = (const float*)d_in[10];
    const float* l2w = (const float*)d_in[11];
    const float* l2b = (const float*)d_in[12];
    (void)in_sizes; (void)n_in; (void)out_size; (void)ws_size;

    // workspace layout (~92 MB); xg aliases bufB (dead until agg2 writes it)
    char* ws = (char*)d_ws;
    size_t off = 0;
    auto alloc = [&](size_t bytes) -> void* {
        void* p = ws + off;
        off = (off + bytes + 255) & ~(size_t)255;
        return p;
    };
    float*              bufA   = (float*)             alloc((size_t)NTOT  * DIM_ * 4);
    float*              bufB   = (float*)             alloc((size_t)N2TOT * DIM_ * 4);
    unsigned int*       blist  = (unsigned int*)      alloc((size_t)B_ * CHUNKS_ * BCAP * 4);
    unsigned int*       xb     = (unsigned int*)      alloc((size_t)NTOT * 32 * 4);
    int*                bcnt   = (int*)               alloc((size_t)B_ * SLICES_ * CHUNKS_ * 4);
    int*                ninfo  = (int*)               alloc((size_t)NTOT * 4);
    float*              score  = (float*)             alloc((size_t)NTOT * 4);
    int*                newid  = (int*)               alloc((size_t)NTOT * 4);
    unsigned long long* thr    = (unsigned long long*)alloc((size_t)B_ * 8);
    float*              part1  = (float*)             alloc((size_t)B_ * PB_ * 128 * 4);
    float*              part2  = (float*)             alloc((size_t)B_ * PB_ * 128 * 4);
    unsigned int*       xg     = (unsigned int*)bufB;   // alias

    // ---- stage 1 ----
    k_bucket<1><<<B_ * SLICES_, 256, 0, stream>>>(src, dst, nullptr, bcnt, blist);
    k_sort<1><<<B_ * CHUNKS_, 256, 0, stream>>>(bcnt, blist, x, nullptr, xb, ninfo);
    k_agg<false><<<NTOT / 8, 256, 0, stream>>>(xb, ninfo, blist, bufA);
    k_convrow<<<NTOT / 64, 256, 0, stream>>>(bufA, W1, b1, p1, score, NTOT);
    k_thresh<1><<<B_, 256, 0, stream>>>(score, thr);
    k_pool<1><<<B_ * PB_, 256, 0, stream>>>(score, bufA, thr, newid, xg, part1);

    // ---- stage 2 ----
    k_bucket<2><<<B_ * SLICES_, 256, 0, stream>>>(src, dst, newid, bcnt, blist);
    k_sort<2><<<B_ * CHUNKS_, 256, 0, stream>>>(bcnt, blist, nullptr, xg, xb, ninfo);
    k_agg<true><<<205 * B_, 256, 0, stream>>>(xb, ninfo, blist, bufB);
    k_convrow<<<N2TOT / 64, 256, 0, stream>>>(bufB, W2, b2, p2, score, N2TOT);
    k_thresh<2><<<B_, 256, 0, stream>>>(score, thr);
    k_pool<2><<<B_ * PB_, 256, 0, stream>>>(score, bufB, thr, nullptr, nullptr, part2);

    // ---- head (combines both stages' partials) ----
    k_head<<<B_, 64, 0, stream>>>(part1, part2, l1w, l1b, l2w, l2b, (float*)d_out);
}